// Round 3
// baseline (667.310 us; speedup 1.0000x reference)
//
#include <hip/hip_runtime.h>

typedef short bf16x8 __attribute__((ext_vector_type(8)));
typedef float f32x4 __attribute__((ext_vector_type(4)));

#define B_ 32
#define T_ 2048
#define C_ 1024
#define H_ 64

__device__ __forceinline__ ushort f2bf(float f) {
  union { float f; unsigned u; } v; v.f = f;
  unsigned u = v.u;
  return (ushort)((u + 0x7FFFu + ((u >> 16) & 1u)) >> 16);
}

__device__ __forceinline__ void async_copy16(void* lds, const void* g) {
  __builtin_amdgcn_global_load_lds(
      (const __attribute__((address_space(1))) unsigned int*)g,
      (__attribute__((address_space(3))) unsigned int*)lds, 16, 0, 0);
}

// Wt[n][c], n = mat*64 + h, mat: 0=Wk, 1=Wq (scaled by 1/8*log2e), 2=Wv
__global__ __launch_bounds__(256) void wconv_kernel(
    const float* __restrict__ Wk, const float* __restrict__ Wq,
    const float* __restrict__ Wv, ushort* __restrict__ Wt) {
  int idx = blockIdx.x * 256 + threadIdx.x;
  if (idx >= 3 * 64 * C_) return;
  int n = idx >> 10, c = idx & 1023;
  int mat = n >> 6, h = n & 63;
  const float* W = (mat == 0) ? Wk : (mat == 1 ? Wq : Wv);
  float v = W[c * 64 + h];
  if (mat == 1) v *= 0.18033688011112042f;  // 8^-1 * log2(e)
  Wt[idx] = f2bf(v);
}

// QKV projection. A (x) staged via global_load_lds, XOR-swizzled 16B chunks,
// two 32KB half-buffers per barrier pair (128 k per sync). B (Wt) direct from
// global (L1/L2-hot: 24KB slice shared by all resident waves).
// V written transposed: Vt[b][h][t].
__global__ __launch_bounds__(256) void qkv_kernel(
    const float* __restrict__ x, const ushort* __restrict__ Wt,
    ushort* __restrict__ Kb, ushort* __restrict__ Qb, ushort* __restrict__ Vt) {
  __shared__ __align__(16) float As[2][128 * 64];  // 64 KB
  int tid = threadIdx.x;
  int wave = tid >> 6, lane = tid & 63, quad = lane >> 4, l16 = lane & 15;
  int r0 = blockIdx.x * 128;

  f32x4 acc[2][12];
#pragma unroll
  for (int rt = 0; rt < 2; ++rt)
#pragma unroll
    for (int nt = 0; nt < 12; ++nt) acc[rt][nt] = (f32x4){0.f, 0.f, 0.f, 0.f};

  for (int k0 = 0; k0 < C_; k0 += 128) {
    __syncthreads();
    // stage 128 rows x 128 k of x; chunk (16B=4 fp32) at pos p holds data
    // chunk c = p ^ (row&15)  -> conflict-free b128 frag reads
#pragma unroll
    for (int i = 0; i < 8; ++i) {
      int id = tid + 256 * i;
      int r = id >> 4, p = id & 15;
      int c = p ^ (r & 15);
      async_copy16((char*)(&As[0][0]) + id * 16,
                   x + (size_t)(r0 + r) * C_ + k0 + c * 4);
    }
#pragma unroll
    for (int i = 0; i < 8; ++i) {
      int id = tid + 256 * i;
      int r = id >> 4, p = id & 15;
      int c = p ^ (r & 15);
      async_copy16((char*)(&As[1][0]) + id * 16,
                   x + (size_t)(r0 + r) * C_ + k0 + 64 + c * 4);
    }
    __syncthreads();

#pragma unroll
    for (int half = 0; half < 2; ++half) {
      int kbase = k0 + half * 64;
#pragma unroll
      for (int ks = 0; ks < 2; ++ks) {
        bf16x8 af[2];
#pragma unroll
        for (int rt = 0; rt < 2; ++rt) {
          int row = wave * 32 + rt * 16 + l16;
          int c0 = ks * 8 + quad * 2;
          f32x4 a0 = *(const f32x4*)(&As[half][row * 64 + ((c0 ^ l16) << 2)]);
          f32x4 a1 = *(const f32x4*)(&As[half][row * 64 + (((c0 + 1) ^ l16) << 2)]);
          bf16x8 t;
          t[0] = (short)f2bf(a0[0]); t[1] = (short)f2bf(a0[1]);
          t[2] = (short)f2bf(a0[2]); t[3] = (short)f2bf(a0[3]);
          t[4] = (short)f2bf(a1[0]); t[5] = (short)f2bf(a1[1]);
          t[6] = (short)f2bf(a1[2]); t[7] = (short)f2bf(a1[3]);
          af[rt] = t;
        }
#pragma unroll
        for (int nt = 0; nt < 12; ++nt) {
          bf16x8 bf = *(const bf16x8*)(Wt + (size_t)(nt * 16 + l16) * C_ +
                                       kbase + ks * 32 + quad * 8);
          acc[0][nt] = __builtin_amdgcn_mfma_f32_16x16x32_bf16(af[0], bf, acc[0][nt], 0, 0, 0);
          acc[1][nt] = __builtin_amdgcn_mfma_f32_16x16x32_bf16(af[1], bf, acc[1][nt], 0, 0, 0);
        }
      }
    }
  }

  // epilogue. C layout: col(h) = l16, row = quad*4 + r
  int b = r0 >> 11;
#pragma unroll
  for (int rt = 0; rt < 2; ++rt) {
    int rowbase = r0 + wave * 32 + rt * 16 + quad * 4;
#pragma unroll
    for (int nt = 0; nt < 12; ++nt) {
      int mat = nt >> 2;
      int h = (nt & 3) * 16 + l16;
      if (mat == 2) {  // V: packed 4x bf16 store along t
        ushort4 pv;
        pv.x = f2bf(acc[rt][nt][0]); pv.y = f2bf(acc[rt][nt][1]);
        pv.z = f2bf(acc[rt][nt][2]); pv.w = f2bf(acc[rt][nt][3]);
        *(ushort4*)(&Vt[(size_t)b * H_ * T_ + (size_t)h * T_ + (rowbase & (T_ - 1))]) = pv;
      } else {
        ushort* dst = (mat == 0) ? Kb : Qb;
#pragma unroll
        for (int r = 0; r < 4; ++r)
          dst[(size_t)(rowbase + r) * H_ + h] = f2bf(acc[rt][nt][r]);
      }
    }
  }
}

// Flash attention, barrier-free. 64 q-rows/block (4 waves x 16 rows), KV-tile 64.
// XCD-aware swizzle: batch = (bx&7)+8*(by&3) keeps each XCD's K/V set at 2MB (L2-hot).
__global__ __launch_bounds__(256) void attn_kernel(
    const ushort* __restrict__ Qb, const ushort* __restrict__ Kb,
    const ushort* __restrict__ Vt, float* __restrict__ out) {
  __shared__ __align__(16) ushort Pl[4 * 16 * 80];

  int tid = threadIdx.x;
  int wave = tid >> 6, lane = tid & 63, quad = lane >> 4, l16 = lane & 15;
  int bx = blockIdx.x, by = blockIdx.y;
  int batch = (bx & 7) + 8 * (by & 3);
  int qseg = (bx >> 3) + 4 * (by >> 2);
  int q0 = qseg * 64 + wave * 16;
  const ushort* Qbase = Qb + (size_t)batch * T_ * H_;
  const ushort* Kbase = Kb + (size_t)batch * T_ * H_;
  const ushort* Vbase = Vt + (size_t)batch * H_ * T_;
  ushort* Pw = Pl + wave * 16 * 80;

  const ushort* qr = Qbase + (size_t)(q0 + l16) * H_;
  bf16x8 qf0 = *(const bf16x8*)(qr + quad * 8);
  bf16x8 qf1 = *(const bf16x8*)(qr + 32 + quad * 8);

  f32x4 o[4];
  float m_i[4], l_i[4];
#pragma unroll
  for (int i = 0; i < 4; ++i) {
    o[i] = (f32x4){0.f, 0.f, 0.f, 0.f};
    m_i[i] = -1e30f; l_i[i] = 0.f;
  }

  int jb_last = q0 >> 6;
  for (int jb = 0; jb <= jb_last; ++jb) {
    int j0 = jb * 64;

    // V^T frags first: independent of S, overlap the softmax VALU chain
    bf16x8 vf[4][2];
#pragma unroll
    for (int ht = 0; ht < 4; ++ht) {
      const ushort* vr = Vbase + (size_t)(ht * 16 + l16) * T_ + j0;
      vf[ht][0] = *(const bf16x8*)(vr + quad * 8);
      vf[ht][1] = *(const bf16x8*)(vr + 32 + quad * 8);
    }

    // S = Q K^T : lane holds rows q = quad*4+rr, col j = nt*16+l16
    f32x4 sv[4];
#pragma unroll
    for (int nt = 0; nt < 4; ++nt) {
      const ushort* kr = Kbase + (size_t)(j0 + nt * 16 + l16) * H_;
      bf16x8 kf0 = *(const bf16x8*)(kr + quad * 8);
      bf16x8 kf1 = *(const bf16x8*)(kr + 32 + quad * 8);
      f32x4 z = (f32x4){0.f, 0.f, 0.f, 0.f};
      z = __builtin_amdgcn_mfma_f32_16x16x32_bf16(qf0, kf0, z, 0, 0, 0);
      z = __builtin_amdgcn_mfma_f32_16x16x32_bf16(qf1, kf1, z, 0, 0, 0);
      sv[nt] = z;
    }

    if (jb == jb_last) {  // causal mask on diagonal block
      int rowg = q0 + quad * 4;
#pragma unroll
      for (int nt = 0; nt < 4; ++nt) {
        int col = j0 + nt * 16 + l16;
#pragma unroll
        for (int rr = 0; rr < 4; ++rr)
          if (col > rowg + rr) sv[nt][rr] = -1e30f;
      }
    }

    // online softmax (base-2; 1/8*log2e folded into Wq)
    float alpha[4];
#pragma unroll
    for (int rr = 0; rr < 4; ++rr) {
      float v = fmaxf(fmaxf(sv[0][rr], sv[1][rr]), fmaxf(sv[2][rr], sv[3][rr]));
      v = fmaxf(v, __shfl_xor(v, 1));
      v = fmaxf(v, __shfl_xor(v, 2));
      v = fmaxf(v, __shfl_xor(v, 4));
      v = fmaxf(v, __shfl_xor(v, 8));
      float mn = fmaxf(m_i[rr], v);
      alpha[rr] = exp2f(m_i[rr] - mn);
      m_i[rr] = mn;
    }
    float rsum[4] = {0.f, 0.f, 0.f, 0.f};
#pragma unroll
    for (int nt = 0; nt < 4; ++nt)
#pragma unroll
      for (int rr = 0; rr < 4; ++rr) {
        float p = exp2f(sv[nt][rr] - m_i[rr]);
        rsum[rr] += p;
        Pw[(quad * 4 + rr) * 80 + nt * 16 + l16] = f2bf(p);
      }
#pragma unroll
    for (int rr = 0; rr < 4; ++rr) l_i[rr] = alpha[rr] * l_i[rr] + rsum[rr];
#pragma unroll
    for (int ht = 0; ht < 4; ++ht)
#pragma unroll
      for (int rr = 0; rr < 4; ++rr) o[ht][rr] *= alpha[rr];

    // P: C-layout -> per-wave LDS -> A-layout (no barrier: same-wave RW)
    bf16x8 pf0 = *(const bf16x8*)(&Pw[l16 * 80 + quad * 8]);
    bf16x8 pf1 = *(const bf16x8*)(&Pw[l16 * 80 + 32 + quad * 8]);
#pragma unroll
    for (int ht = 0; ht < 4; ++ht) {
      o[ht] = __builtin_amdgcn_mfma_f32_16x16x32_bf16(pf0, vf[ht][0], o[ht], 0, 0, 0);
      o[ht] = __builtin_amdgcn_mfma_f32_16x16x32_bf16(pf1, vf[ht][1], o[ht], 0, 0, 0);
    }
  }

  // finalize: reduce per-lane l partials across the 16 j-lanes
#pragma unroll
  for (int rr = 0; rr < 4; ++rr) {
    float v = l_i[rr];
    v += __shfl_xor(v, 1);
    v += __shfl_xor(v, 2);
    v += __shfl_xor(v, 4);
    v += __shfl_xor(v, 8);
    l_i[rr] = __builtin_amdgcn_rcpf(v);
  }
  int rowbase = q0 + quad * 4;
#pragma unroll
  for (int ht = 0; ht < 4; ++ht)
#pragma unroll
    for (int rr = 0; rr < 4; ++rr)
      out[((size_t)batch * T_ + rowbase + rr) * H_ + ht * 16 + l16] =
          o[ht][rr] * l_i[rr];
}

extern "C" void kernel_launch(void* const* d_in, const int* in_sizes, int n_in,
                              void* d_out, int out_size, void* d_ws, size_t ws_size,
                              hipStream_t stream) {
  const float* x  = (const float*)d_in[0];
  const float* Wk = (const float*)d_in[1];
  const float* Wq = (const float*)d_in[2];
  const float* Wv = (const float*)d_in[3];
  float* out = (float*)d_out;

  ushort* Wt = (ushort*)d_ws;                              // 384 KB
  ushort* Kb = (ushort*)((char*)d_ws + (1 << 19));         // 8 MB each
  ushort* Qb = Kb + (size_t)B_ * T_ * H_;
  ushort* Vt = Qb + (size_t)B_ * T_ * H_;                  // transposed [b][h][t]

  hipLaunchKernelGGL(wconv_kernel, dim3(768), dim3(256), 0, stream, Wk, Wq, Wv, Wt);
  hipLaunchKernelGGL(qkv_kernel, dim3(512), dim3(256), 0, stream, x, Wt, Kb, Qb, Vt);
  hipLaunchKernelGGL(attn_kernel, dim3(32, 32), dim3(256), 0, stream, Qb, Kb, Vt, out);
}

// Round 4
// 451.269 us; speedup vs baseline: 1.4787x; 1.4787x over previous
//
#include <hip/hip_runtime.h>
#include <hip/hip_bf16.h>

typedef short bf16x8 __attribute__((ext_vector_type(8)));
typedef float f32x4 __attribute__((ext_vector_type(4)));

#define B_ 32
#define T_ 2048
#define C_ 1024
#define H_ 64

__device__ __forceinline__ ushort f2bf(float f) {
  union { float f; unsigned u; } v; v.f = f;
  unsigned u = v.u;
  return (ushort)((u + 0x7FFFu + ((u >> 16) & 1u)) >> 16);
}

__device__ __forceinline__ bf16x8 pack8(float4 a, float4 b) {
  union { __hip_bfloat162 h; short2 s; } t;
  bf16x8 r;
  t.h = __float22bfloat162_rn(make_float2(a.x, a.y)); r[0] = t.s.x; r[1] = t.s.y;
  t.h = __float22bfloat162_rn(make_float2(a.z, a.w)); r[2] = t.s.x; r[3] = t.s.y;
  t.h = __float22bfloat162_rn(make_float2(b.x, b.y)); r[4] = t.s.x; r[5] = t.s.y;
  t.h = __float22bfloat162_rn(make_float2(b.z, b.w)); r[6] = t.s.x; r[7] = t.s.y;
  return r;
}

__device__ __forceinline__ void async_copy16(void* lds, const void* g) {
  __builtin_amdgcn_global_load_lds(
      (const __attribute__((address_space(1))) unsigned int*)g,
      (__attribute__((address_space(3))) unsigned int*)lds, 16, 0, 0);
}

// Wt[n][c], n = mat*64 + h, mat: 0=Wk, 1=Wq (scaled by 1/8*log2e), 2=Wv
__global__ __launch_bounds__(256) void wconv_kernel(
    const float* __restrict__ Wk, const float* __restrict__ Wq,
    const float* __restrict__ Wv, ushort* __restrict__ Wt) {
  int idx = blockIdx.x * 256 + threadIdx.x;
  if (idx >= 3 * 64 * C_) return;
  int n = idx >> 10, c = idx & 1023;
  int mat = n >> 6, h = n & 63;
  const float* W = (mat == 0) ? Wk : (mat == 1 ? Wq : Wv);
  float v = W[c * 64 + h];
  if (mat == 1) v *= 0.18033688011112042f;  // 8^-1 * log2(e)
  Wt[idx] = f2bf(v);
}

// QKV projection. B (Wt, latency-critical: L2-thrashed by x stream) staged in
// LDS per BK=64 via async copy, XOR-swizzled. A (x) loaded direct to VGPRs
// before the drain barrier (latency absorbed by the same drain). 64 rows/block,
// 4 waves x 16 rows x 192 cols; 24 KB LDS -> 4 blocks/CU for overlap.
__global__ __launch_bounds__(256, 4) void qkv_kernel(
    const float* __restrict__ x, const ushort* __restrict__ Wt,
    ushort* __restrict__ Kb, ushort* __restrict__ Qb, ushort* __restrict__ Vt) {
  __shared__ __align__(16) ushort Bs[192 * 64];  // 24 KB
  int tid = threadIdx.x;
  int wave = tid >> 6, lane = tid & 63, quad = lane >> 4, l16 = lane & 15;
  int r0 = blockIdx.x * 64;
  const float* xr = x + (size_t)(r0 + wave * 16 + l16) * C_;

  f32x4 acc[12];
#pragma unroll
  for (int nt = 0; nt < 12; ++nt) acc[nt] = (f32x4){0.f, 0.f, 0.f, 0.f};

  for (int k0 = 0; k0 < C_; k0 += 64) {
    __syncthreads();  // all waves done reading previous B tile
    // stage B: 192 rows x 8 chunks (16B = 8 bf16); src chunk c = p ^ (n&7)
#pragma unroll
    for (int i = 0; i < 6; ++i) {
      int id = tid + 256 * i;
      int n = id >> 3, p = id & 7, c = p ^ (n & 7);
      async_copy16((char*)Bs + id * 16, Wt + (size_t)n * C_ + k0 + c * 8);
    }
    // A frags direct from global; drained by the same barrier
    float4 a0 = *(const float4*)(xr + k0 + quad * 8);
    float4 a1 = *(const float4*)(xr + k0 + quad * 8 + 4);
    float4 a2 = *(const float4*)(xr + k0 + 32 + quad * 8);
    float4 a3 = *(const float4*)(xr + k0 + 32 + quad * 8 + 4);
    __syncthreads();  // B staged (vmcnt(0) drain also covers A loads)

    bf16x8 af0 = pack8(a0, a1);
    bf16x8 af1 = pack8(a2, a3);
#pragma unroll
    for (int nt = 0; nt < 12; ++nt) {
      int n = nt * 16 + l16;  // n&7 == l16&7
      bf16x8 b0 = *(const bf16x8*)(Bs + n * 64 + ((quad ^ (l16 & 7)) << 3));
      bf16x8 b1 = *(const bf16x8*)(Bs + n * 64 + (((4 + quad) ^ (l16 & 7)) << 3));
      acc[nt] = __builtin_amdgcn_mfma_f32_16x16x32_bf16(af0, b0, acc[nt], 0, 0, 0);
      acc[nt] = __builtin_amdgcn_mfma_f32_16x16x32_bf16(af1, b1, acc[nt], 0, 0, 0);
    }
  }

  // epilogue. C layout: col(h) = l16, row = quad*4 + r
  int b = r0 >> 11;
  int rowbase = r0 + wave * 16 + quad * 4;
#pragma unroll
  for (int nt = 0; nt < 12; ++nt) {
    int mat = nt >> 2;
    int h = (nt & 3) * 16 + l16;
    if (mat == 2) {  // V: packed 4x bf16 store along t (transposed layout)
      ushort4 pv;
      pv.x = f2bf(acc[nt][0]); pv.y = f2bf(acc[nt][1]);
      pv.z = f2bf(acc[nt][2]); pv.w = f2bf(acc[nt][3]);
      *(ushort4*)(&Vt[(size_t)b * H_ * T_ + (size_t)h * T_ + (rowbase & (T_ - 1))]) = pv;
    } else {
      ushort* dst = (mat == 0) ? Kb : Qb;
#pragma unroll
      for (int r = 0; r < 4; ++r)
        dst[(size_t)(rowbase + r) * H_ + h] = f2bf(acc[nt][r]);
    }
  }
}

// Flash attention. K and V^T tiles staged cooperatively in LDS (4x traffic cut
// vs per-wave global reads), XOR-swizzled for conflict-free b128 frag reads.
// P round-trips per-wave LDS (no barrier). Heavy q-segments dispatched first.
__global__ __launch_bounds__(256, 4) void attn_kernel(
    const ushort* __restrict__ Qb, const ushort* __restrict__ Kb,
    const ushort* __restrict__ Vt, float* __restrict__ out) {
  __shared__ __align__(16) ushort Ks[64 * 64];      // 8 KB: K[j][h]
  __shared__ __align__(16) ushort Vs[64 * 64];      // 8 KB: V^T[h][j]
  __shared__ __align__(16) ushort Pl[4 * 16 * 80];  // 10 KB

  int tid = threadIdx.x;
  int wave = tid >> 6, lane = tid & 63, quad = lane >> 4, l16 = lane & 15;
  int bx = blockIdx.x, by = blockIdx.y;
  int batch = (bx & 7) + 8 * (by & 3);        // XCD-aware: 4 batches per XCD
  int qseg = 31 - ((bx >> 3) + 4 * (by >> 2));  // heavy segments first
  int q0 = qseg * 64 + wave * 16;
  const ushort* Qbase = Qb + (size_t)batch * T_ * H_;
  const ushort* Kbase = Kb + (size_t)batch * T_ * H_;
  const ushort* Vbase = Vt + (size_t)batch * H_ * T_;
  ushort* Pw = Pl + wave * 16 * 80;

  const ushort* qr = Qbase + (size_t)(q0 + l16) * H_;
  bf16x8 qf0 = *(const bf16x8*)(qr + quad * 8);
  bf16x8 qf1 = *(const bf16x8*)(qr + 32 + quad * 8);

  f32x4 o[4];
  float m_i[4], l_i[4];
#pragma unroll
  for (int i = 0; i < 4; ++i) {
    o[i] = (f32x4){0.f, 0.f, 0.f, 0.f};
    m_i[i] = -1e30f; l_i[i] = 0.f;
  }

  int jb_last = qseg;  // uniform across the block's 4 waves
  for (int jb = 0; jb <= jb_last; ++jb) {
    int j0 = jb * 64;
    __syncthreads();  // previous tile's reads complete
    // stage K[j][h] and V^T[h][j] tiles; src chunk c = p ^ (row&7)
#pragma unroll
    for (int g = 0; g < 2; ++g) {
      int id = tid + 256 * g;
      int r = id >> 3, p = id & 7, c = p ^ (r & 7);
      async_copy16((char*)Ks + id * 16, Kbase + (size_t)(j0 + r) * H_ + c * 8);
      async_copy16((char*)Vs + id * 16, Vbase + (size_t)r * T_ + j0 + c * 8);
    }
    __syncthreads();  // tiles staged

    // S = Q K^T : lane holds rows q = quad*4+rr, col j = nt*16+l16
    f32x4 sv[4];
#pragma unroll
    for (int nt = 0; nt < 4; ++nt) {
      int n = nt * 16 + l16;  // n&7 == l16&7
      bf16x8 kf0 = *(const bf16x8*)(Ks + n * 64 + ((quad ^ (l16 & 7)) << 3));
      bf16x8 kf1 = *(const bf16x8*)(Ks + n * 64 + (((4 + quad) ^ (l16 & 7)) << 3));
      f32x4 z = (f32x4){0.f, 0.f, 0.f, 0.f};
      z = __builtin_amdgcn_mfma_f32_16x16x32_bf16(qf0, kf0, z, 0, 0, 0);
      z = __builtin_amdgcn_mfma_f32_16x16x32_bf16(qf1, kf1, z, 0, 0, 0);
      sv[nt] = z;
    }

    if (jb == jb_last) {  // causal mask on diagonal block
      int rowg = q0 + quad * 4;
#pragma unroll
      for (int nt = 0; nt < 4; ++nt) {
        int col = j0 + nt * 16 + l16;
#pragma unroll
        for (int rr = 0; rr < 4; ++rr)
          if (col > rowg + rr) sv[nt][rr] = -1e30f;
      }
    }

    // online softmax (base-2; 1/8*log2e folded into Wq)
    float alpha[4];
#pragma unroll
    for (int rr = 0; rr < 4; ++rr) {
      float v = fmaxf(fmaxf(sv[0][rr], sv[1][rr]), fmaxf(sv[2][rr], sv[3][rr]));
      v = fmaxf(v, __shfl_xor(v, 1));
      v = fmaxf(v, __shfl_xor(v, 2));
      v = fmaxf(v, __shfl_xor(v, 4));
      v = fmaxf(v, __shfl_xor(v, 8));
      float mn = fmaxf(m_i[rr], v);
      alpha[rr] = exp2f(m_i[rr] - mn);
      m_i[rr] = mn;
    }
    float rsum[4] = {0.f, 0.f, 0.f, 0.f};
#pragma unroll
    for (int nt = 0; nt < 4; ++nt)
#pragma unroll
      for (int rr = 0; rr < 4; ++rr) {
        float p = exp2f(sv[nt][rr] - m_i[rr]);
        rsum[rr] += p;
        Pw[(quad * 4 + rr) * 80 + nt * 16 + l16] = f2bf(p);
      }
#pragma unroll
    for (int rr = 0; rr < 4; ++rr) l_i[rr] = alpha[rr] * l_i[rr] + rsum[rr];
#pragma unroll
    for (int ht = 0; ht < 4; ++ht)
#pragma unroll
      for (int rr = 0; rr < 4; ++rr) o[ht][rr] *= alpha[rr];

    // P: C-layout -> per-wave LDS -> A-layout (no barrier: same-wave RW)
    bf16x8 pf0 = *(const bf16x8*)(&Pw[l16 * 80 + quad * 8]);
    bf16x8 pf1 = *(const bf16x8*)(&Pw[l16 * 80 + 32 + quad * 8]);
#pragma unroll
    for (int ht = 0; ht < 4; ++ht) {
      int hrow = ht * 16 + l16;  // hrow&7 == l16&7
      bf16x8 vf0 = *(const bf16x8*)(Vs + hrow * 64 + ((quad ^ (l16 & 7)) << 3));
      bf16x8 vf1 = *(const bf16x8*)(Vs + hrow * 64 + (((4 + quad) ^ (l16 & 7)) << 3));
      o[ht] = __builtin_amdgcn_mfma_f32_16x16x32_bf16(pf0, vf0, o[ht], 0, 0, 0);
      o[ht] = __builtin_amdgcn_mfma_f32_16x16x32_bf16(pf1, vf1, o[ht], 0, 0, 0);
    }
  }

  // finalize: reduce per-lane l partials across the 16 j-lanes
#pragma unroll
  for (int rr = 0; rr < 4; ++rr) {
    float v = l_i[rr];
    v += __shfl_xor(v, 1);
    v += __shfl_xor(v, 2);
    v += __shfl_xor(v, 4);
    v += __shfl_xor(v, 8);
    l_i[rr] = __builtin_amdgcn_rcpf(v);
  }
  int rowbase = q0 + quad * 4;
#pragma unroll
  for (int ht = 0; ht < 4; ++ht)
#pragma unroll
    for (int rr = 0; rr < 4; ++rr)
      out[((size_t)batch * T_ + rowbase + rr) * H_ + ht * 16 + l16] =
          o[ht][rr] * l_i[rr];
}

extern "C" void kernel_launch(void* const* d_in, const int* in_sizes, int n_in,
                              void* d_out, int out_size, void* d_ws, size_t ws_size,
                              hipStream_t stream) {
  const float* x  = (const float*)d_in[0];
  const float* Wk = (const float*)d_in[1];
  const float* Wq = (const float*)d_in[2];
  const float* Wv = (const float*)d_in[3];
  float* out = (float*)d_out;

  ushort* Wt = (ushort*)d_ws;                              // 384 KB
  ushort* Kb = (ushort*)((char*)d_ws + (1 << 19));         // 8 MB each
  ushort* Qb = Kb + (size_t)B_ * T_ * H_;
  ushort* Vt = Qb + (size_t)B_ * T_ * H_;                  // transposed [b][h][t]

  hipLaunchKernelGGL(wconv_kernel, dim3(768), dim3(256), 0, stream, Wk, Wq, Wv, Wt);
  hipLaunchKernelGGL(qkv_kernel, dim3(1024), dim3(256), 0, stream, x, Wt, Kb, Qb, Vt);
  hipLaunchKernelGGL(attn_kernel, dim3(32, 32), dim3(256), 0, stream, Qb, Kb, Vt, out);
}